// Round 19
// baseline (80.154 us; speedup 1.0000x reference)
//
#include <hip/hip_runtime.h>

#define C_IN 64
#define C_OUT 8
#define IMG 128
#define HW (IMG * IMG)
#define BATCH 32
#define K_STEPS 8

#define FEAT_BYTES ((size_t)BATCH * HW * C_OUT * 4)   // 16,777,216
#define BLK_PER_B 8
#define NROUNDS (K_STEPS - 1)
#define NFLAGS (NROUNDS * BATCH * BLK_PER_B)          // 1792 u64
#define NZERO (NFLAGS + BATCH)                        // + done[32]
#define NT 1024
#define CHUNK (HW / BLK_PER_B)                        // 2048 px per block

union F2U { float2 f2; unsigned long long u; };
__device__ __forceinline__ void nt_store2(float* p, float a, float b2) {
    F2U v; v.f2 = make_float2(a, b2);
    __builtin_nontemporal_store(v.u, (unsigned long long*)p);
}

// Tiny pre-kernel: zero step-flags + done-counters each launch (stream-
// ordered before the merged kernel) => graph-replay safe.
__global__ __launch_bounds__(256) void zero_flags_kernel(
    unsigned long long* __restrict__ flags)
{
    const int i = blockIdx.x * 256 + threadIdx.x;
    if (i < NZERO) flags[i] = 0ULL;
}

// ---------------------------------------------------------------------------
// Merged co-resident kernel, grid 512 x 1024:
//   blocks 0..255  : SEMICONV role — 8 blocks/batch, 2 adjacent px/thread,
//                    float2 x-loads, conv math bit-identical to the
//                    validated r10 kernel (per-pixel fmaf chains unchanged);
//                    step-0 rand-argmax candidate -> seed0; after feat
//                    stores: barrier (drains stores to L2), release fence,
//                    relaxed done[b]++.
//   blocks 256..511: STICK role — EXACT r18 body. Pre-spin: rand load +
//                    scope-0 store (overlaps conv). Spin: tid0 RELAXED-polls
//                    done[b]==8 (15 waves parked at barrier; no fence in the
//                    loop), then ONE acquire fence, barrier, feat loads.
// DEADLOCK-FREE BY CAPACITY: __launch_bounds__(1024,8) caps VGPR at 64 for
// both roles => 2 blocks/CU => all 512 blocks resident simultaneously,
// independent of dispatch order => producers always progress.
// XCD locality: both roles map batch b to XCD b%8 (bid%8==b%8), so feat,
// flags, and done stay L2-local; correctness does not depend on this
// (release/acquire fences carry cross-XCD visibility).
// argmax / alpha / log1pf math bitwise identical to the validated r5-r18
// path ((max,min-idx) total order is reduction-topology independent; the
// 8-slot seed0 partition replaces 16 slots — same unique winner).
// ---------------------------------------------------------------------------
__global__ __launch_bounds__(NT, 8) void fused_pipeline_kernel(
    const float* __restrict__ x,           // [B][C_IN][HW]
    const float* __restrict__ w,           // [C_OUT][C_IN]
    const float* __restrict__ bias,        // [C_OUT]
    const float* __restrict__ gate_p,      // scalar
    const float* __restrict__ rand_pixel,  // [B][HW]
    const float* __restrict__ log_sigma_p, // scalar
    float* __restrict__ masks,             // [B][K][HW]
    float* __restrict__ scopes,            // [B][K][HW]
    unsigned long long* __restrict__ flags,// [7][B][BLK_PER_B]
    unsigned long long* __restrict__ done, // [B]
    unsigned long long* __restrict__ seed0,// [B][8]
    float* __restrict__ feat)              // [B][HW][C_OUT]
{
    __shared__ float sw[C_OUT * C_IN];
    __shared__ float spv[16];
    __shared__ int   spi[16];
    __shared__ float swv[2][16];
    __shared__ int   swi[2][16];
    __shared__ int   sSeed[2];

    const int tid  = threadIdx.x;
    const int lane = tid & 63;
    const int wid  = tid >> 6;

    if (blockIdx.x < 256) {
        // ================= SEMICONV role =================
        const int b    = blockIdx.x & 31;
        const int blk8 = blockIdx.x >> 5;          // 0..7
        const int p0   = blk8 * CHUNK + 2 * tid;   // adjacent px p0, p0+1

        if (tid < C_OUT * C_IN) sw[tid] = w[tid];

        // step-0 seed candidate: argmax of raw rand (== rand*expf(0))
        {
            const float2 rv = *(const float2*)(rand_pixel + (size_t)b * HW + p0);
            float bv = rv.x; int bi = p0;
            if (rv.y > bv) { bv = rv.y; bi = p0 + 1; }   // ascending, strict >
            #pragma unroll
            for (int off = 1; off < 64; off <<= 1) {
                const float ov = __shfl_xor(bv, off);
                const int   oi = __shfl_xor(bi, off);
                if (ov > bv || (ov == bv && oi < bi)) { bv = ov; bi = oi; }
            }
            if (lane == 0) { spv[wid] = bv; spi[wid] = bi; }
        }
        __syncthreads();   // covers sw staging AND spv/spi
        if (tid == 0) {
            float v = spv[0]; int ix = spi[0];
            #pragma unroll
            for (int t = 1; t < 16; ++t) {
                if (spv[t] > v || (spv[t] == v && spi[t] < ix)) { v = spv[t]; ix = spi[t]; }
            }
            seed0[(b << 3) | blk8] =
                ((unsigned long long)__float_as_uint(v) << 32) |
                (unsigned long long)(unsigned int)ix;
        }

        const float gate = *gate_p;
        const float* xb = x + (size_t)b * C_IN * HW + p0;

        float a0[C_OUT], a1[C_OUT];
        #pragma unroll
        for (int o = 0; o < C_OUT; ++o) { const float bv = bias[o]; a0[o] = bv; a1[o] = bv; }

        for (int c = 0; c < C_IN; ++c) {
            const float2 xv = *(const float2*)(xb + (size_t)c * HW);
            #pragma unroll
            for (int o = 0; o < C_OUT; ++o) {
                const float wv = sw[o * C_IN + c];
                a0[o] = fmaf(wv, xv.x, a0[o]);
                a1[o] = fmaf(wv, xv.y, a1[o]);
            }
        }

        const int row = p0 >> 7;
        const int col = p0 & 127;                  // p0 even => col, col+1 same row
        const float step = 2.0f / (IMG - 1);
        const float g1 = -1.0f + step * (float)row;

        float* dst = feat + ((size_t)b * HW + p0) * C_OUT;
        {
            float o0 = gate * a0[0], o1 = gate * a0[1], o2 = gate * a0[2], o3 = gate * a0[3];
            float o4 = gate * a0[4], o5 = gate * a0[5];
            float o6 = gate * a0[6] + g1;
            float o7 = gate * a0[7] + (-1.0f + step * (float)col);
            *(float4*)(dst)     = make_float4(o0, o1, o2, o3);
            *(float4*)(dst + 4) = make_float4(o4, o5, o6, o7);
        }
        {
            float o0 = gate * a1[0], o1 = gate * a1[1], o2 = gate * a1[2], o3 = gate * a1[3];
            float o4 = gate * a1[4], o5 = gate * a1[5];
            float o6 = gate * a1[6] + g1;
            float o7 = gate * a1[7] + (-1.0f + step * (float)(col + 1));
            *(float4*)(dst + 8)  = make_float4(o0, o1, o2, o3);
            *(float4*)(dst + 12) = make_float4(o4, o5, o6, o7);
        }

        __syncthreads();   // every wave's feat stores drained (vmcnt) to L2
        if (tid == 0) {
            __builtin_amdgcn_fence(__ATOMIC_RELEASE, "agent");   // push to device scope
            __hip_atomic_fetch_add(&done[b], 1ULL,
                                   __ATOMIC_RELAXED, __HIP_MEMORY_SCOPE_AGENT);
        }
        return;
    }

    // ================= STICK role (r18 body + gated start) =================
    const int sid = blockIdx.x - 256;
    const int b   = sid & 31;
    const int blk = sid >> 5;

    const float inv_sigma = expf(-(*log_sigma_p));

    // hoisted clamped-case log1pf values (r18; laundered => device libm,
    // bit-identical to the in-loop calls they replace)
    float c01 = -0.01f, c99 = -0.99f;
    asm volatile("" : "+v"(c01), "+v"(c99));
    const float DLS_LO = log1pf(c01);
    const float DLS_HI = log1pf(c99);

    const float* fb = feat + (size_t)b * HW * C_OUT;
    const float* rb = rand_pixel + (size_t)b * HW;
    float* mb = masks  + (size_t)b * (K_STEPS * HW);
    float* sb = scopes + (size_t)b * (K_STEPS * HW);

    const int p0 = blk * CHUNK + 2 * tid;

    // pre-spin work (overlaps producer's conv)
    const float2 rr = *(const float2*)(rb + p0);
    nt_store2(sb + p0, 0.0f, 0.0f);        // log_scopes[:,0] = 0

    // gate on producer completion: relaxed spin (no fence in loop), one
    // acquire fence after, barrier wakes the parked waves.
    if (tid == 0) {
        unsigned long long d;
        do {
            d = __hip_atomic_load(&done[b], __ATOMIC_RELAXED,
                                  __HIP_MEMORY_SCOPE_AGENT);
        } while (d < (unsigned long long)BLK_PER_B);
        __builtin_amdgcn_fence(__ATOMIC_ACQUIRE, "agent");
    }
    __syncthreads();

    const float4 f0a = *(const float4*)(fb + (size_t)p0 * C_OUT);
    const float4 f0b = *(const float4*)(fb + (size_t)p0 * C_OUT + 4);
    const float4 f1a = *(const float4*)(fb + (size_t)p0 * C_OUT + 8);
    const float4 f1b = *(const float4*)(fb + (size_t)p0 * C_OUT + 12);

    float ls0 = 0.0f, ls1 = 0.0f;

    for (int s = 0; s < NROUNDS; ++s) {
        const int par = s & 1;
        int seedIdx;

        if (s == 0) {
            // seed precomputed by the producer blocks: reduce 8 slots
            float gv = -1.0f; int gi = 0x7fffffff;
            if (lane < BLK_PER_B) {
                const unsigned long long got = seed0[(b << 3) | lane];
                gv = __uint_as_float((unsigned int)(got >> 32));
                gi = (int)(unsigned int)(got & 0xffffffffULL);
            }
            #pragma unroll
            for (int off = 1; off < 8; off <<= 1) {
                const float ov = __shfl_xor(gv, off);
                const int   oi = __shfl_xor(gi, off);
                if (ov > gv || (ov == gv && oi < gi)) { gv = ov; gi = oi; }
            }
            seedIdx = __shfl(gi, 0);
        } else {
            const int recbase = (s * BATCH + b) * BLK_PER_B;

            // ---- per-thread argmax of rand * exp(log_scope) ----
            float bv; int bi;
            {
                const float v0 = rr.x * expf(ls0);
                const float v1 = rr.y * expf(ls1);
                bv = v0; bi = p0;
                if (v1 > bv) { bv = v1; bi = p0 + 1; }  // strict > keeps lower idx
            }
            #pragma unroll
            for (int off = 1; off < 64; off <<= 1) {
                const float ov = __shfl_xor(bv, off);
                const int   oi = __shfl_xor(bi, off);
                if (ov > bv || (ov == bv && oi < bi)) { bv = ov; bi = oi; }
            }
            if (lane == 0) { swv[par][wid] = bv; swi[par][wid] = bi; }
            __syncthreads();               // barrier 1

            // ---- wave 0: reduce, publish, poll peers, global reduce ----
            if (wid == 0) {
                float v = (lane < 16) ? swv[par][lane] : -1.0f;
                int   ix = (lane < 16) ? swi[par][lane] : 0x7fffffff;
                #pragma unroll
                for (int off = 1; off < 16; off <<= 1) {
                    const float ov = __shfl_xor(v, off);
                    const int   oi = __shfl_xor(ix, off);
                    if (ov > v || (ov == v && oi < ix)) { v = ov; ix = oi; }
                }
                if (lane == 0) {
                    const unsigned long long pk =
                        ((unsigned long long)__float_as_uint(v) << 32) |
                        (unsigned long long)(unsigned int)(ix + 1);
                    __hip_atomic_store(&flags[recbase + blk], pk,
                                       __ATOMIC_RELAXED, __HIP_MEMORY_SCOPE_AGENT);
                }
                float gv = -1.0f; int gi = 0x7fffffff;
                if (lane < BLK_PER_B) {
                    unsigned long long got;
                    do {
                        got = __hip_atomic_load(&flags[recbase + lane],
                                                __ATOMIC_RELAXED,
                                                __HIP_MEMORY_SCOPE_AGENT);
                    } while (got == 0ULL);
                    gv = __uint_as_float((unsigned int)(got >> 32));
                    gi = (int)(unsigned int)(got & 0xffffffffULL) - 1;
                }
                #pragma unroll
                for (int off = 1; off < 8; off <<= 1) {
                    const float ov = __shfl_xor(gv, off);
                    const int   oi = __shfl_xor(gi, off);
                    if (ov > gv || (ov == gv && oi < gi)) { gv = ov; gi = oi; }
                }
                if (lane == 0) sSeed[par] = gi;
            }
            __syncthreads();               // barrier 2
            seedIdx = sSeed[par];
        }

        // seed features (uniform address -> broadcast load, L2/L3-hot)
        const float4 s0 = *(const float4*)(fb + (size_t)seedIdx * C_OUT);
        const float4 s1 = *(const float4*)(fb + (size_t)seedIdx * C_OUT + 4);

        // ---- distances, alpha, mask/scope update (validated math) ----
        float sq0 = 0.0f, sq1 = 0.0f, d;
        d = f0a.x - s0.x; sq0 += d * d;
        d = f0a.y - s0.y; sq0 += d * d;
        d = f0a.z - s0.z; sq0 += d * d;
        d = f0a.w - s0.w; sq0 += d * d;
        d = f0b.x - s1.x; sq0 += d * d;
        d = f0b.y - s1.y; sq0 += d * d;
        d = f0b.z - s1.z; sq0 += d * d;
        d = f0b.w - s1.w; sq0 += d * d;
        d = f1a.x - s0.x; sq1 += d * d;
        d = f1a.y - s0.y; sq1 += d * d;
        d = f1a.z - s0.z; sq1 += d * d;
        d = f1a.w - s0.w; sq1 += d * d;
        d = f1b.x - s1.x; sq1 += d * d;
        d = f1b.y - s1.y; sq1 += d * d;
        d = f1b.z - s1.z; sq1 += d * d;
        d = f1b.w - s1.w; sq1 += d * d;

        float m0, m1;
        {
            const float t = sq0 * inv_sigma;
            const float alpha = expf(-t);
            float log_a, dls;
            if (alpha >= 0.99f)      { log_a = -0.010050336f; dls = DLS_HI; } // ln(0.99)
            else if (alpha <= 0.01f) { log_a = -4.6051702f;   dls = DLS_LO; } // ln(0.01)
            else                     { log_a = -t; dls = log1pf(-alpha); }
            m0 = ls0 + log_a;
            ls0 += dls;
        }
        {
            const float t = sq1 * inv_sigma;
            const float alpha = expf(-t);
            float log_a, dls;
            if (alpha >= 0.99f)      { log_a = -0.010050336f; dls = DLS_HI; }
            else if (alpha <= 0.01f) { log_a = -4.6051702f;   dls = DLS_LO; }
            else                     { log_a = -t; dls = log1pf(-alpha); }
            m1 = ls1 + log_a;
            ls1 += dls;
        }
        nt_store2(mb + s * HW + p0, m0, m1);
        nt_store2(sb + (s + 1) * HW + p0, ls0, ls1);
    }

    nt_store2(mb + (K_STEPS - 1) * HW + p0, ls0, ls1);  // last mask = final scope
}

extern "C" void kernel_launch(void* const* d_in, const int* in_sizes, int n_in,
                              void* d_out, int out_size, void* d_ws, size_t ws_size,
                              hipStream_t stream) {
    const float* x          = (const float*)d_in[0];  // [32,64,128,128]
    const float* rand_pixel = (const float*)d_in[1];  // [32,1,128,128]
    const float* conv_w     = (const float*)d_in[2];  // [8,64]
    const float* conv_b     = (const float*)d_in[3];  // [8]
    const float* gate       = (const float*)d_in[4];  // scalar
    const float* log_sigma  = (const float*)d_in[5];  // scalar

    float* masks  = (float*)d_out;                          // [32,8,128,128]
    float* scopes = masks + (long long)BATCH * K_STEPS * HW;

    float* feat = (float*)d_ws;  // 16.8 MB
    unsigned long long* flags =
        (unsigned long long*)((char*)d_ws + FEAT_BYTES);    // 1792 u64
    unsigned long long* done  = flags + NFLAGS;             // 32 u64
    unsigned long long* seed0 = done + BATCH;               // 256 u64

    zero_flags_kernel<<<(NZERO + 255) / 256, 256, 0, stream>>>(flags);

    fused_pipeline_kernel<<<512, NT, 0, stream>>>(
        x, conv_w, conv_b, gate, rand_pixel, log_sigma,
        masks, scopes, flags, done, seed0, feat);
}

// Round 20
// 62.260 us; speedup vs baseline: 1.2874x; 1.2874x over previous
//
#include <hip/hip_runtime.h>

#define C_IN 64
#define C_OUT 8
#define IMG 128
#define HW (IMG * IMG)
#define BATCH 32
#define K_STEPS 8

#define FEAT_BYTES ((size_t)BATCH * HW * C_OUT * 4)   // 16,777,216
#define BLK_PER_B 8
#define NROUNDS (K_STEPS - 1)
#define NFLAGS (NROUNDS * BATCH * BLK_PER_B)          // 1792 u64

union F2U { float2 f2; unsigned long long u; };
__device__ __forceinline__ void nt_store2(float* p, float a, float b2) {
    F2U v; v.f2 = make_float2(a, b2);
    __builtin_nontemporal_store(v.u, (unsigned long long*)p);
}

// ---------------------------------------------------------------------------
// Kernel A (r10, validated): 1x1 conv + gate + bias + coords; step-0
// rand-argmax per block -> seed0[]; block 0 zeroes the flags.
// ---------------------------------------------------------------------------
__global__ __launch_bounds__(256) void semiconv_kernel(
    const float* __restrict__ x,      // [B][C_IN][HW]
    const float* __restrict__ w,      // [C_OUT][C_IN]
    const float* __restrict__ bias,   // [C_OUT]
    const float* __restrict__ gate_p, // scalar
    const float* __restrict__ rand_pixel, // [B][HW]
    float* __restrict__ feat,         // [B][HW][C_OUT]
    unsigned long long* __restrict__ flags,
    unsigned long long* __restrict__ seed0)
{
    __shared__ float sw[C_OUT * C_IN];
    __shared__ float spv[4];
    __shared__ int   spi[4];
    const int tid = threadIdx.x;
    if (blockIdx.x == 0) {
        for (int k = tid; k < NFLAGS; k += 256) flags[k] = 0ULL;
    }
    for (int i = tid; i < C_OUT * C_IN; i += 256) sw[i] = w[i];

    const int b     = blockIdx.x >> 4;
    const int blk16 = blockIdx.x & 15;
    const int p4    = ((blk16 * 256) + tid) * 4;
    const int lane  = tid & 63;
    const int wid   = tid >> 6;

    {
        const float4 rv = *(const float4*)(rand_pixel + (size_t)b * HW + p4);
        float bv = rv.x; int bi = p4;
        if (rv.y > bv) { bv = rv.y; bi = p4 + 1; }   // ascending, strict >
        if (rv.z > bv) { bv = rv.z; bi = p4 + 2; }
        if (rv.w > bv) { bv = rv.w; bi = p4 + 3; }
        #pragma unroll
        for (int off = 1; off < 64; off <<= 1) {
            const float ov = __shfl_xor(bv, off);
            const int   oi = __shfl_xor(bi, off);
            if (ov > bv || (ov == bv && oi < bi)) { bv = ov; bi = oi; }
        }
        if (lane == 0) { spv[wid] = bv; spi[wid] = bi; }
    }
    __syncthreads();   // covers sw staging AND spv/spi
    if (tid == 0) {
        float v = spv[0]; int ix = spi[0];
        #pragma unroll
        for (int wv2 = 1; wv2 < 4; ++wv2) {
            if (spv[wv2] > v || (spv[wv2] == v && spi[wv2] < ix)) { v = spv[wv2]; ix = spi[wv2]; }
        }
        seed0[(b << 4) | blk16] =
            ((unsigned long long)__float_as_uint(v) << 32) |
            (unsigned long long)(unsigned int)ix;
    }

    const float gate = *gate_p;
    const float* xb = x + (long long)b * C_IN * HW + p4;

    float acc[C_OUT][4];
    #pragma unroll
    for (int o = 0; o < C_OUT; ++o) {
        const float bv = bias[o];
        #pragma unroll
        for (int j = 0; j < 4; ++j) acc[o][j] = bv;
    }

    for (int c = 0; c < C_IN; ++c) {
        const float4 xv = *(const float4*)(xb + c * HW);
        const float xs[4] = {xv.x, xv.y, xv.z, xv.w};
        #pragma unroll
        for (int o = 0; o < C_OUT; ++o) {
            const float wv = sw[o * C_IN + c];
            #pragma unroll
            for (int j = 0; j < 4; ++j) acc[o][j] = fmaf(wv, xs[j], acc[o][j]);
        }
    }

    const int row  = p4 / IMG;
    const int col0 = p4 % IMG;
    const float step = 2.0f / (IMG - 1);
    const float g1 = -1.0f + step * (float)row;

    float* dst = feat + ((long long)b * HW + p4) * C_OUT;
    #pragma unroll
    for (int j = 0; j < 4; ++j) {
        float o0 = gate * acc[0][j];
        float o1 = gate * acc[1][j];
        float o2 = gate * acc[2][j];
        float o3 = gate * acc[3][j];
        float o4 = gate * acc[4][j];
        float o5 = gate * acc[5][j];
        float o6 = gate * acc[6][j] + g1;
        float o7 = gate * acc[7][j] + (-1.0f + step * (float)(col0 + j));
        *(float4*)(dst + j * C_OUT)     = make_float4(o0, o1, o2, o3);
        *(float4*)(dst + j * C_OUT + 4) = make_float4(o4, o5, o6, o7);
    }
}

// ---------------------------------------------------------------------------
// Kernel B (r18, validated 63.9us): r10 structure + sync protocol; clamped-
// case log1pf results hoisted to per-thread init (laundered through asm so
// they are computed by the DEVICE libm => bit-identical ls trajectory).
// Clamped pixels run dist -> t -> v_exp -> compare -> add-const; mid-range
// pixels keep the exact in-loop log1pf(-alpha).
// ---------------------------------------------------------------------------
#define NT 1024
#define CHUNK (HW / BLK_PER_B)   // 2048

__global__ __launch_bounds__(NT) void stick_kernel(
    const float* __restrict__ feat,        // [B][HW][C_OUT]
    const float* __restrict__ rand_pixel,  // [B][HW]
    const float* __restrict__ log_sigma_p, // scalar
    float* __restrict__ masks,             // [B][K][HW]
    float* __restrict__ scopes,            // [B][K][HW]
    unsigned long long* __restrict__ flags,// [7][B][BLK_PER_B]
    const unsigned long long* __restrict__ seed0) // [B][16]
{
    // batch b's 8 blocks share blockIdx%8 -> same XCD (L2-local flags).
    const int b    = blockIdx.x & 31;
    const int blk  = blockIdx.x >> 5;
    const int tid  = threadIdx.x;
    const int lane = tid & 63;
    const int wid  = tid >> 6;             // 0..15

    const float inv_sigma = expf(-(*log_sigma_p));

    // hoisted clamped-case log1pf values (device libm, bit-identical)
    float c01 = -0.01f, c99 = -0.99f;
    asm volatile("" : "+v"(c01), "+v"(c99));
    const float DLS_LO = log1pf(c01);      // ls-delta when alpha clamps to 0.01
    const float DLS_HI = log1pf(c99);      // ls-delta when alpha clamps to 0.99

    const float* fb = feat + (size_t)b * HW * C_OUT;
    const float* rb = rand_pixel + (size_t)b * HW;
    float* mb = masks  + (size_t)b * (K_STEPS * HW);
    float* sb = scopes + (size_t)b * (K_STEPS * HW);

    const int p0 = blk * CHUNK + 2 * tid;  // adjacent pixels p0, p0+1

    const float4 f0a = *(const float4*)(fb + (size_t)p0 * C_OUT);
    const float4 f0b = *(const float4*)(fb + (size_t)p0 * C_OUT + 4);
    const float4 f1a = *(const float4*)(fb + (size_t)p0 * C_OUT + 8);
    const float4 f1b = *(const float4*)(fb + (size_t)p0 * C_OUT + 12);

    const float2 rr = *(const float2*)(rb + p0);
    float ls0 = 0.0f, ls1 = 0.0f;
    nt_store2(sb + p0, 0.0f, 0.0f);        // log_scopes[:,0] = 0

    __shared__ float swv[2][16];
    __shared__ int   swi[2][16];
    __shared__ int   sSeed[2];

    for (int s = 0; s < NROUNDS; ++s) {
        const int par = s & 1;
        int seedIdx;

        if (s == 0) {
            // seed precomputed by semiconv: reduce 16 slots, no sync
            float gv = -1.0f; int gi = 0x7fffffff;
            if (lane < 16) {
                const unsigned long long got = seed0[(b << 4) | lane];
                gv = __uint_as_float((unsigned int)(got >> 32));
                gi = (int)(unsigned int)(got & 0xffffffffULL);
            }
            #pragma unroll
            for (int off = 1; off < 16; off <<= 1) {
                const float ov = __shfl_xor(gv, off);
                const int   oi = __shfl_xor(gi, off);
                if (ov > gv || (ov == gv && oi < gi)) { gv = ov; gi = oi; }
            }
            seedIdx = __shfl(gi, 0);
        } else {
            const int recbase = (s * BATCH + b) * BLK_PER_B;

            // ---- per-thread argmax of rand * exp(log_scope) ----
            float bv; int bi;
            {
                const float v0 = rr.x * expf(ls0);
                const float v1 = rr.y * expf(ls1);
                bv = v0; bi = p0;
                if (v1 > bv) { bv = v1; bi = p0 + 1; }  // strict > keeps lower idx
            }
            #pragma unroll
            for (int off = 1; off < 64; off <<= 1) {
                const float ov = __shfl_xor(bv, off);
                const int   oi = __shfl_xor(bi, off);
                if (ov > bv || (ov == bv && oi < bi)) { bv = ov; bi = oi; }
            }
            if (lane == 0) { swv[par][wid] = bv; swi[par][wid] = bi; }
            __syncthreads();               // barrier 1

            // ---- wave 0: reduce, publish, poll peers, global reduce ----
            if (wid == 0) {
                float v = (lane < 16) ? swv[par][lane] : -1.0f;
                int   ix = (lane < 16) ? swi[par][lane] : 0x7fffffff;
                #pragma unroll
                for (int off = 1; off < 16; off <<= 1) {
                    const float ov = __shfl_xor(v, off);
                    const int   oi = __shfl_xor(ix, off);
                    if (ov > v || (ov == v && oi < ix)) { v = ov; ix = oi; }
                }
                if (lane == 0) {
                    const unsigned long long pk =
                        ((unsigned long long)__float_as_uint(v) << 32) |
                        (unsigned long long)(unsigned int)(ix + 1);
                    __hip_atomic_store(&flags[recbase + blk], pk,
                                       __ATOMIC_RELAXED, __HIP_MEMORY_SCOPE_AGENT);
                }
                float gv = -1.0f; int gi = 0x7fffffff;
                if (lane < BLK_PER_B) {
                    unsigned long long got;
                    do {
                        got = __hip_atomic_load(&flags[recbase + lane],
                                                __ATOMIC_RELAXED,
                                                __HIP_MEMORY_SCOPE_AGENT);
                    } while (got == 0ULL);
                    gv = __uint_as_float((unsigned int)(got >> 32));
                    gi = (int)(unsigned int)(got & 0xffffffffULL) - 1;
                }
                #pragma unroll
                for (int off = 1; off < 8; off <<= 1) {
                    const float ov = __shfl_xor(gv, off);
                    const int   oi = __shfl_xor(gi, off);
                    if (ov > gv || (ov == gv && oi < gi)) { gv = ov; gi = oi; }
                }
                if (lane == 0) sSeed[par] = gi;
            }
            __syncthreads();               // barrier 2
            seedIdx = sSeed[par];
        }

        // seed features (uniform address -> broadcast load, L2/L3-hot)
        const float4 s0 = *(const float4*)(fb + (size_t)seedIdx * C_OUT);
        const float4 s1 = *(const float4*)(fb + (size_t)seedIdx * C_OUT + 4);

        // ---- distances, alpha, mask/scope update ----
        float sq0 = 0.0f, sq1 = 0.0f, d;
        d = f0a.x - s0.x; sq0 += d * d;
        d = f0a.y - s0.y; sq0 += d * d;
        d = f0a.z - s0.z; sq0 += d * d;
        d = f0a.w - s0.w; sq0 += d * d;
        d = f0b.x - s1.x; sq0 += d * d;
        d = f0b.y - s1.y; sq0 += d * d;
        d = f0b.z - s1.z; sq0 += d * d;
        d = f0b.w - s1.w; sq0 += d * d;
        d = f1a.x - s0.x; sq1 += d * d;
        d = f1a.y - s0.y; sq1 += d * d;
        d = f1a.z - s0.z; sq1 += d * d;
        d = f1a.w - s0.w; sq1 += d * d;
        d = f1b.x - s1.x; sq1 += d * d;
        d = f1b.y - s1.y; sq1 += d * d;
        d = f1b.z - s1.z; sq1 += d * d;
        d = f1b.w - s1.w; sq1 += d * d;

        float m0, m1;
        {
            const float t = sq0 * inv_sigma;
            const float alpha = expf(-t);
            float log_a, dls;
            if (alpha >= 0.99f)      { log_a = -0.010050336f; dls = DLS_HI; } // ln(0.99)
            else if (alpha <= 0.01f) { log_a = -4.6051702f;   dls = DLS_LO; } // ln(0.01)
            else                     { log_a = -t; dls = log1pf(-alpha); }
            m0 = ls0 + log_a;
            ls0 += dls;
        }
        {
            const float t = sq1 * inv_sigma;
            const float alpha = expf(-t);
            float log_a, dls;
            if (alpha >= 0.99f)      { log_a = -0.010050336f; dls = DLS_HI; }
            else if (alpha <= 0.01f) { log_a = -4.6051702f;   dls = DLS_LO; }
            else                     { log_a = -t; dls = log1pf(-alpha); }
            m1 = ls1 + log_a;
            ls1 += dls;
        }
        nt_store2(mb + s * HW + p0, m0, m1);
        nt_store2(sb + (s + 1) * HW + p0, ls0, ls1);
    }

    nt_store2(mb + (K_STEPS - 1) * HW + p0, ls0, ls1);  // last mask = final scope
}

extern "C" void kernel_launch(void* const* d_in, const int* in_sizes, int n_in,
                              void* d_out, int out_size, void* d_ws, size_t ws_size,
                              hipStream_t stream) {
    const float* x          = (const float*)d_in[0];  // [32,64,128,128]
    const float* rand_pixel = (const float*)d_in[1];  // [32,1,128,128]
    const float* conv_w     = (const float*)d_in[2];  // [8,64]
    const float* conv_b     = (const float*)d_in[3];  // [8]
    const float* gate       = (const float*)d_in[4];  // scalar
    const float* log_sigma  = (const float*)d_in[5];  // scalar

    float* masks  = (float*)d_out;                          // [32,8,128,128]
    float* scopes = masks + (long long)BATCH * K_STEPS * HW;

    float* feat = (float*)d_ws;  // 16.8 MB
    unsigned long long* flags =
        (unsigned long long*)((char*)d_ws + FEAT_BYTES);               // 14 KB
    unsigned long long* seed0 = flags + NFLAGS;                        // 4 KB

    semiconv_kernel<<<(BATCH * HW) / (256 * 4), 256, 0, stream>>>(
        x, conv_w, conv_b, gate, rand_pixel, feat, flags, seed0);

    stick_kernel<<<BATCH * BLK_PER_B, NT, 0, stream>>>(
        feat, rand_pixel, log_sigma, masks, scopes, flags, seed0);
}